// Round 1
// baseline (734.028 us; speedup 1.0000x reference)
//
#include <hip/hip_runtime.h>
#include <hip/hip_bf16.h>
#include <math.h>

#define BGRAPH 512
#define NNODE  100
#define EPG    1600
#define DIM    128
#define ETOT   (BGRAPH * EPG)   // 819200
#define PAD    132              // 128 + 4: rows stay 16B aligned, banks spread
#define K1     80
#define K2     64
#define NTHREADS 512
#define NWAVE  8
#define MNODES 13               // ceil(100/8)

__global__ __launch_bounds__(NTHREADS) void fused_gnn(
    const int*   __restrict__ x_idx,
    const int*   __restrict__ edge_index,
    const float* __restrict__ emb,
    const float* __restrict__ Wl,
    const float* __restrict__ blv,
    const float* __restrict__ Wr,
    const float* __restrict__ pw1,
    const float* __restrict__ pw2,
    const float* __restrict__ W1,
    const float* __restrict__ b1g,
    const float* __restrict__ W3,
    const float* __restrict__ b3g,
    float*       __restrict__ out)
{
    __shared__ __align__(16) float h0[NNODE * PAD];   // emb rows, later hnew
    __shared__ __align__(16) float agg[NNODE * PAD];  // edge sums, later mean
    __shared__ ushort se[EPG], de[EPG];
    __shared__ float deg[NNODE];
    __shared__ float score1[NNODE], q2[NNODE], s2v[NNODE];
    __shared__ int   rank1[NNODE], rank2[NNODE];
    __shared__ float redm1[4 * DIM], reds1[4 * DIM], redm2[4 * DIM], reds2[4 * DIM];
    __shared__ float xv[2 * DIM];

    const int g    = blockIdx.x;
    const int tid  = threadIdx.x;
    const int lane = tid & 63;
    const int wv   = tid >> 6;

    // ---- zero agg + deg ----
    float4* agg4 = reinterpret_cast<float4*>(agg);
    for (int i = tid; i < NNODE * PAD / 4; i += NTHREADS) agg4[i] = float4{0, 0, 0, 0};
    if (tid < NNODE) deg[tid] = 0.0f;
    __syncthreads();

    // ---- stage embeddings (float4 gather) + edges (+degree) ----
    {
        const float4* emb4 = reinterpret_cast<const float4*>(emb);
        for (int i = tid; i < NNODE * (DIM / 4); i += NTHREADS) {
            int n = i >> 5;        // /32 float4 per row
            int q = i & 31;
            int row = x_idx[g * NNODE + n];
            float4 v = emb4[row * (DIM / 4) + q];
            *reinterpret_cast<float4*>(&h0[n * PAD + q * 4]) = v;
        }
        for (int i = tid; i < EPG; i += NTHREADS) {
            int s = edge_index[g * EPG + i] - g * NNODE;
            int d = edge_index[ETOT + g * EPG + i] - g * NNODE;
            se[i] = (ushort)s;
            de[i] = (ushort)d;
            atomicAdd(&deg[d], 1.0f);
        }
    }
    __syncthreads();

    // ---- SAGE mean-aggregate: per-wave edge, lanes = features (l, l+64) ----
    for (int e = wv; e < EPG; e += NWAVE) {
        int s = se[e];
        int d = de[e];
        float v0 = h0[s * PAD + lane];
        float v1 = h0[s * PAD + lane + 64];
        atomicAdd(&agg[d * PAD + lane], v0);
        atomicAdd(&agg[d * PAD + lane + 64], v1);
    }
    __syncthreads();

    // ---- divide by degree -> mean (in place) ----
    for (int i = tid; i < NNODE * DIM; i += NTHREADS) {
        int n = i >> 7, f = i & 127;
        agg[n * PAD + f] = agg[n * PAD + f] / fmaxf(deg[n], 1.0f);
    }
    __syncthreads();

    // ---- hnew = relu(mean@Wl + bl + h0@Wr), overwrite h0 (rows are wave-owned) ----
    {
        int  nodeIdx[MNODES];
        bool nodeValid[MNODES];
#pragma unroll
        for (int m = 0; m < MNODES; ++m) {
            int n = wv + m * NWAVE;
            nodeValid[m] = (n < NNODE);
            nodeIdx[m]   = nodeValid[m] ? n : 0;
        }
        float accA[MNODES], accB[MNODES];
#pragma unroll
        for (int m = 0; m < MNODES; ++m) { accA[m] = 0.0f; accB[m] = 0.0f; }

        for (int k = 0; k < DIM; k += 4) {
            float wlA[4], wlB[4], wrA[4], wrB[4];
#pragma unroll
            for (int u = 0; u < 4; ++u) {
                wlA[u] = Wl[(k + u) * DIM + lane];
                wlB[u] = Wl[(k + u) * DIM + lane + 64];
                wrA[u] = Wr[(k + u) * DIM + lane];
                wrB[u] = Wr[(k + u) * DIM + lane + 64];
            }
#pragma unroll
            for (int m = 0; m < MNODES; ++m) {
                const float4 mk = *reinterpret_cast<const float4*>(&agg[nodeIdx[m] * PAD + k]);
                const float4 hk = *reinterpret_cast<const float4*>(&h0[nodeIdx[m] * PAD + k]);
                accA[m] += mk.x * wlA[0] + mk.y * wlA[1] + mk.z * wlA[2] + mk.w * wlA[3]
                         + hk.x * wrA[0] + hk.y * wrA[1] + hk.z * wrA[2] + hk.w * wrA[3];
                accB[m] += mk.x * wlB[0] + mk.y * wlB[1] + mk.z * wlB[2] + mk.w * wlB[3]
                         + hk.x * wrB[0] + hk.y * wrB[1] + hk.z * wrB[2] + hk.w * wrB[3];
            }
        }
        float blA = blv[lane], blB = blv[lane + 64];
#pragma unroll
        for (int m = 0; m < MNODES; ++m) {
            if (nodeValid[m]) {
                int n = nodeIdx[m];
                h0[n * PAD + lane]      = fmaxf(accA[m] + blA, 0.0f);
                h0[n * PAD + lane + 64] = fmaxf(accB[m] + blB, 0.0f);
            }
        }
    }
    __syncthreads();

    // ---- pooling scores: score1 = tanh(h.pw1/||pw1||), q2 = h.pw2/||pw2|| ----
    {
        float a1 = pw1[lane], c1 = pw1[lane + 64];
        float a2 = pw2[lane], c2 = pw2[lane + 64];
        float n1 = a1 * a1 + c1 * c1;
        float n2 = a2 * a2 + c2 * c2;
#pragma unroll
        for (int off = 32; off; off >>= 1) {
            n1 += __shfl_xor(n1, off);
            n2 += __shfl_xor(n2, off);
        }
        float rn1 = 1.0f / sqrtf(n1);
        float rn2 = 1.0f / sqrtf(n2);

        for (int n = wv; n < NNODE; n += NWAVE) {
            float hA = h0[n * PAD + lane], hB = h0[n * PAD + lane + 64];
            float d1 = hA * a1 + hB * c1;
            float d2 = hA * a2 + hB * c2;
#pragma unroll
            for (int off = 32; off; off >>= 1) {
                d1 += __shfl_xor(d1, off);
                d2 += __shfl_xor(d2, off);
            }
            if (lane == 0) {
                score1[n] = tanhf(d1 * rn1);
                q2[n]     = d2 * rn2;
            }
        }
    }
    __syncthreads();

    // ---- rank1 (stable top-K1 by counting) + s2 values ----
    if (tid < NNODE) {
        float si = score1[tid];
        int r = 0;
        for (int j = 0; j < NNODE; ++j) {
            float sj = score1[j];
            r += (sj > si || (sj == si && j < tid)) ? 1 : 0;
        }
        rank1[tid] = r;
        // hp1 row = h*val1 -> score2_pre = val1 * (h.pw2)/||pw2||
        s2v[tid] = tanhf(score1[tid] * q2[tid]);
    }
    __syncthreads();

    // ---- rank2 among selected (ties by rank1 position = reference order) ----
    if (tid < NNODE) {
        int r1i = rank1[tid];
        if (r1i < K1) {
            float si = s2v[tid];
            int r = 0;
            for (int j = 0; j < NNODE; ++j) {
                if (rank1[j] < K1) {
                    float sj = s2v[j];
                    r += (sj > si || (sj == si && rank1[j] < r1i)) ? 1 : 0;
                }
            }
            rank2[tid] = r;
        } else {
            rank2[tid] = 1 << 30;
        }
    }
    __syncthreads();

    // ---- readouts: x1 = [max, mean] over top-K1 scaled; x2 over top-K2 doubly scaled ----
    {
        int f = tid & 127;
        int c = tid >> 7;  // 0..3
        float mx1 = -INFINITY, sm1 = 0.0f, mx2 = -INFINITY, sm2 = 0.0f;
        for (int n = c; n < NNODE; n += 4) {
            if (rank1[n] < K1) {
                float v1 = h0[n * PAD + f] * score1[n];
                mx1 = fmaxf(mx1, v1);
                sm1 += v1;
                if (rank2[n] < K2) {
                    float v2 = v1 * s2v[n];
                    mx2 = fmaxf(mx2, v2);
                    sm2 += v2;
                }
            }
        }
        redm1[c * DIM + f] = mx1; reds1[c * DIM + f] = sm1;
        redm2[c * DIM + f] = mx2; reds2[c * DIM + f] = sm2;
    }
    __syncthreads();
    if (tid < DIM) {
        float mx1 = -INFINITY, sm1 = 0.0f, mx2 = -INFINITY, sm2 = 0.0f;
#pragma unroll
        for (int c = 0; c < 4; ++c) {
            mx1 = fmaxf(mx1, redm1[c * DIM + tid]); sm1 += reds1[c * DIM + tid];
            mx2 = fmaxf(mx2, redm2[c * DIM + tid]); sm2 += reds2[c * DIM + tid];
        }
        xv[tid]       = mx1 + mx2;
        xv[DIM + tid] = sm1 * (1.0f / K1) + sm2 * (1.0f / K2);
    }
    __syncthreads();

    // ---- MLP head: y = relu(x@W1+b1); out = sigmoid(y@W3+b3) ----
    if (tid < 64) {
        float acc = b1g[tid];
        for (int f = 0; f < 2 * DIM; ++f) acc += xv[f] * W1[f * 64 + tid];
        float y = fmaxf(acc, 0.0f);
        float r = y * W3[tid];
#pragma unroll
        for (int off = 32; off; off >>= 1) r += __shfl_xor(r, off);
        if (tid == 0) out[g] = 1.0f / (1.0f + expf(-(r + b3g[0])));
    }
}

extern "C" void kernel_launch(void* const* d_in, const int* in_sizes, int n_in,
                              void* d_out, int out_size, void* d_ws, size_t ws_size,
                              hipStream_t stream) {
    const int*   x_idx      = (const int*)d_in[0];
    const int*   edge_index = (const int*)d_in[1];
    // d_in[2] = batch (unused)
    const float* emb = (const float*)d_in[3];
    const float* Wl  = (const float*)d_in[4];
    const float* bl  = (const float*)d_in[5];
    const float* Wr  = (const float*)d_in[6];
    const float* pw1 = (const float*)d_in[7];
    const float* pw2 = (const float*)d_in[8];
    const float* W1  = (const float*)d_in[9];
    const float* b1  = (const float*)d_in[10];
    const float* W3  = (const float*)d_in[11];
    const float* b3  = (const float*)d_in[12];
    float* out = (float*)d_out;

    fused_gnn<<<BGRAPH, NTHREADS, 0, stream>>>(
        x_idx, edge_index, emb, Wl, bl, Wr, pw1, pw2, W1, b1, W3, b3, out);
}

// Round 3
// 221.209 us; speedup vs baseline: 3.3183x; 3.3183x over previous
//
#include <hip/hip_runtime.h>
#include <hip/hip_bf16.h>
#include <math.h>

#define BGRAPH 512
#define NNODE  100
#define EPG    1600
#define DIM    128
#define ETOT   (BGRAPH * EPG)   // 819200
#define PAD    132              // 128 + 4: rows stay 16B aligned, banks spread
#define K1     80
#define K2     64
#define NTHREADS 1024
#define NWAVE  16
#define MNODES 7                // ceil(100/16)

__global__ __launch_bounds__(NTHREADS) void fused_gnn(
    const int*   __restrict__ x_idx,
    const int*   __restrict__ edge_index,
    const float* __restrict__ emb,
    const float* __restrict__ Wl,
    const float* __restrict__ blv,
    const float* __restrict__ Wr,
    const float* __restrict__ pw1,
    const float* __restrict__ pw2,
    const float* __restrict__ W1,
    const float* __restrict__ b1g,
    const float* __restrict__ W3,
    const float* __restrict__ b3g,
    float*       __restrict__ out)
{
    __shared__ __align__(16) float h0[NNODE * PAD];   // emb rows, later hnew
    __shared__ __align__(16) float agg[NNODE * PAD];  // mean rows
    __shared__ ushort csr[EPG];                       // src ids sorted by dst
    __shared__ int off_[NNODE + 1];                   // CSR offsets (exclusive)
    __shared__ int cursor[NNODE];
    __shared__ int degi[NNODE];
    __shared__ int nid[NNODE];
    __shared__ float score1[NNODE], q2[NNODE], s2v[NNODE];
    __shared__ int   rank1[NNODE], rank2[NNODE];
    __shared__ float redm1[8 * DIM], reds1[8 * DIM], redm2[8 * DIM], reds2[8 * DIM];
    __shared__ float xv[2 * DIM];

    const int g    = blockIdx.x;
    const int tid  = threadIdx.x;
    const int lane = tid & 63;
    const int wv   = tid >> 6;

    // ---- phase 1: stage node ids, zero degree ----
    if (tid < NNODE) {
        nid[tid]  = x_idx[g * NNODE + tid];
        degi[tid] = 0;
    }
    __syncthreads();

    // ---- phase 2: gather embeddings (float4) + count in-degrees (int atomics) ----
    {
        const float4* emb4 = reinterpret_cast<const float4*>(emb);
        for (int i = tid; i < NNODE * (DIM / 4); i += NTHREADS) {
            int n = i >> 5;        // float4-quads per row = 32
            int q = i & 31;
            int row = nid[n];
            float4 v = emb4[row * (DIM / 4) + q];
            *reinterpret_cast<float4*>(&h0[n * PAD + q * 4]) = v;
        }
        for (int i = tid; i < EPG; i += NTHREADS) {
            int d = edge_index[ETOT + g * EPG + i] - g * NNODE;
            atomicAdd(&degi[d], 1);
        }
    }
    __syncthreads();

    // ---- phase 3: wave-0 prefix scan of degrees -> CSR offsets + cursors ----
    if (wv == 0) {
        int d0 = (lane < NNODE) ? degi[lane] : 0;
        int s0 = d0;
#pragma unroll
        for (int o = 1; o < 64; o <<= 1) { int t = __shfl_up(s0, o); if (lane >= o) s0 += t; }
        int tot0 = __shfl(s0, 63);
        int d1 = (lane + 64 < NNODE) ? degi[lane + 64] : 0;
        int s1 = d1;
#pragma unroll
        for (int o = 1; o < 64; o <<= 1) { int t = __shfl_up(s1, o); if (lane >= o) s1 += t; }
        s1 += tot0;
        if (lane == 0) off_[0] = 0;
        off_[lane + 1] = s0;
        if (lane + 64 < NNODE) off_[lane + 65] = s1;
        cursor[lane] = s0 - d0;
        if (lane + 64 < NNODE) cursor[lane + 64] = s1 - d1;
    }
    __syncthreads();

    // ---- phase 4: scatter edges into CSR (int cursor atomics) ----
    for (int i = tid; i < EPG; i += NTHREADS) {
        int s = edge_index[g * EPG + i] - g * NNODE;
        int d = edge_index[ETOT + g * EPG + i] - g * NNODE;
        int pos = atomicAdd(&cursor[d], 1);
        csr[pos] = (ushort)s;
    }
    __syncthreads();

    // ---- phase 5: aggregate + mean, no atomics: wave owns destination nodes ----
    for (int m = 0; m < MNODES; ++m) {
        int n = wv + m * NWAVE;
        if (n >= NNODE) break;
        int beg = off_[n], end = off_[n + 1];
        float a0 = 0.0f, a1 = 0.0f;
#pragma unroll 4
        for (int i = beg; i < end; ++i) {
            int s = csr[i];
            a0 += h0[s * PAD + lane];
            a1 += h0[s * PAD + lane + 64];
        }
        float invd = 1.0f / fmaxf((float)(end - beg), 1.0f);
        agg[n * PAD + lane]      = a0 * invd;
        agg[n * PAD + lane + 64] = a1 * invd;
    }
    __syncthreads();

    // ---- phase 6: hnew = relu(mean@Wl + bl + h0@Wr), overwrite h0 (wave-owned rows) ----
    {
        int  nodeIdx[MNODES];
        bool nodeValid[MNODES];
#pragma unroll
        for (int m = 0; m < MNODES; ++m) {
            int n = wv + m * NWAVE;
            nodeValid[m] = (n < NNODE);
            nodeIdx[m]   = nodeValid[m] ? n : 0;
        }
        float accA[MNODES], accB[MNODES];
#pragma unroll
        for (int m = 0; m < MNODES; ++m) { accA[m] = 0.0f; accB[m] = 0.0f; }

        for (int k = 0; k < DIM; k += 4) {
            float wlA[4], wlB[4], wrA[4], wrB[4];
#pragma unroll
            for (int u = 0; u < 4; ++u) {
                wlA[u] = Wl[(k + u) * DIM + lane];
                wlB[u] = Wl[(k + u) * DIM + lane + 64];
                wrA[u] = Wr[(k + u) * DIM + lane];
                wrB[u] = Wr[(k + u) * DIM + lane + 64];
            }
#pragma unroll
            for (int m = 0; m < MNODES; ++m) {
                const float4 mk = *reinterpret_cast<const float4*>(&agg[nodeIdx[m] * PAD + k]);
                const float4 hk = *reinterpret_cast<const float4*>(&h0[nodeIdx[m] * PAD + k]);
                accA[m] += mk.x * wlA[0] + mk.y * wlA[1] + mk.z * wlA[2] + mk.w * wlA[3]
                         + hk.x * wrA[0] + hk.y * wrA[1] + hk.z * wrA[2] + hk.w * wrA[3];
                accB[m] += mk.x * wlB[0] + mk.y * wlB[1] + mk.z * wlB[2] + mk.w * wlB[3]
                         + hk.x * wrB[0] + hk.y * wrB[1] + hk.z * wrB[2] + hk.w * wrB[3];
            }
        }
        float blA = blv[lane], blB = blv[lane + 64];
#pragma unroll
        for (int m = 0; m < MNODES; ++m) {
            if (nodeValid[m]) {
                int n = nodeIdx[m];
                h0[n * PAD + lane]      = fmaxf(accA[m] + blA, 0.0f);
                h0[n * PAD + lane + 64] = fmaxf(accB[m] + blB, 0.0f);
            }
        }
    }
    __syncthreads();

    // ---- phase 7: pooling scores ----
    {
        float a1 = pw1[lane], c1 = pw1[lane + 64];
        float a2 = pw2[lane], c2 = pw2[lane + 64];
        float n1 = a1 * a1 + c1 * c1;
        float n2 = a2 * a2 + c2 * c2;
#pragma unroll
        for (int off = 32; off; off >>= 1) {
            n1 += __shfl_xor(n1, off);
            n2 += __shfl_xor(n2, off);
        }
        float rn1 = 1.0f / sqrtf(n1);
        float rn2 = 1.0f / sqrtf(n2);

        for (int n = wv; n < NNODE; n += NWAVE) {
            float hA = h0[n * PAD + lane], hB = h0[n * PAD + lane + 64];
            float d1 = hA * a1 + hB * c1;
            float d2 = hA * a2 + hB * c2;
#pragma unroll
            for (int off = 32; off; off >>= 1) {
                d1 += __shfl_xor(d1, off);
                d2 += __shfl_xor(d2, off);
            }
            if (lane == 0) {
                score1[n] = tanhf(d1 * rn1);
                q2[n]     = d2 * rn2;
            }
        }
    }
    __syncthreads();

    // ---- phase 8: rank1 (stable top-K1 by counting) + s2 values ----
    if (tid < NNODE) {
        float si = score1[tid];
        int r = 0;
        for (int j = 0; j < NNODE; ++j) {
            float sj = score1[j];
            r += (sj > si || (sj == si && j < tid)) ? 1 : 0;
        }
        rank1[tid] = r;
        s2v[tid] = tanhf(score1[tid] * q2[tid]);
    }
    __syncthreads();

    // ---- phase 9: rank2 among selected (ties by rank1 position) ----
    if (tid < NNODE) {
        int r1i = rank1[tid];
        if (r1i < K1) {
            float si = s2v[tid];
            int r = 0;
            for (int j = 0; j < NNODE; ++j) {
                if (rank1[j] < K1) {
                    float sj = s2v[j];
                    r += (sj > si || (sj == si && rank1[j] < r1i)) ? 1 : 0;
                }
            }
            rank2[tid] = r;
        } else {
            rank2[tid] = 1 << 30;
        }
    }
    __syncthreads();

    // ---- phase 10: readouts ----
    {
        int f = tid & 127;
        int c = tid >> 7;  // 0..7
        float mx1 = -INFINITY, sm1 = 0.0f, mx2 = -INFINITY, sm2 = 0.0f;
        for (int n = c; n < NNODE; n += 8) {
            if (rank1[n] < K1) {
                float v1 = h0[n * PAD + f] * score1[n];
                mx1 = fmaxf(mx1, v1);
                sm1 += v1;
                if (rank2[n] < K2) {
                    float v2 = v1 * s2v[n];
                    mx2 = fmaxf(mx2, v2);
                    sm2 += v2;
                }
            }
        }
        redm1[c * DIM + f] = mx1; reds1[c * DIM + f] = sm1;
        redm2[c * DIM + f] = mx2; reds2[c * DIM + f] = sm2;
    }
    __syncthreads();
    if (tid < DIM) {
        float mx1 = -INFINITY, sm1 = 0.0f, mx2 = -INFINITY, sm2 = 0.0f;
#pragma unroll
        for (int c = 0; c < 8; ++c) {
            mx1 = fmaxf(mx1, redm1[c * DIM + tid]); sm1 += reds1[c * DIM + tid];
            mx2 = fmaxf(mx2, redm2[c * DIM + tid]); sm2 += reds2[c * DIM + tid];
        }
        xv[tid]       = mx1 + mx2;
        xv[DIM + tid] = sm1 * (1.0f / K1) + sm2 * (1.0f / K2);
    }
    __syncthreads();

    // ---- phase 11: MLP head ----
    if (tid < 64) {
        float acc = b1g[tid];
        for (int f = 0; f < 2 * DIM; ++f) acc += xv[f] * W1[f * 64 + tid];
        float y = fmaxf(acc, 0.0f);
        float r = y * W3[tid];
#pragma unroll
        for (int off = 32; off; off >>= 1) r += __shfl_xor(r, off);
        if (tid == 0) out[g] = 1.0f / (1.0f + expf(-(r + b3g[0])));
    }
}

extern "C" void kernel_launch(void* const* d_in, const int* in_sizes, int n_in,
                              void* d_out, int out_size, void* d_ws, size_t ws_size,
                              hipStream_t stream) {
    const int*   x_idx      = (const int*)d_in[0];
    const int*   edge_index = (const int*)d_in[1];
    // d_in[2] = batch (unused)
    const float* emb = (const float*)d_in[3];
    const float* Wl  = (const float*)d_in[4];
    const float* bl  = (const float*)d_in[5];
    const float* Wr  = (const float*)d_in[6];
    const float* pw1 = (const float*)d_in[7];
    const float* pw2 = (const float*)d_in[8];
    const float* W1  = (const float*)d_in[9];
    const float* b1  = (const float*)d_in[10];
    const float* W3  = (const float*)d_in[11];
    const float* b3  = (const float*)d_in[12];
    float* out = (float*)d_out;

    fused_gnn<<<BGRAPH, NTHREADS, 0, stream>>>(
        x_idx, edge_index, emb, Wl, bl, Wr, pw1, pw2, W1, b1, W3, b3, out);
}

// Round 5
// 158.069 us; speedup vs baseline: 4.6437x; 1.3994x over previous
//
#include <hip/hip_runtime.h>
#include <hip/hip_bf16.h>
#include <math.h>

#define BGRAPH 512
#define NNODE  100
#define EPG    1600
#define DIM    128
#define ETOT   (BGRAPH * EPG)   // 819200
#define PAD    132              // floats per row: 16B-aligned rows, uniform bank spread
#define K1     80
#define K2     64
#define NTHREADS 1024

typedef __attribute__((ext_vector_type(8))) short short8;   // 8 bf16 in 4 VGPRs
typedef __attribute__((ext_vector_type(4))) float f32x4;    // MFMA acc

__device__ __forceinline__ ushort bf16_rne(float x) {
    unsigned u = __float_as_uint(x);
    u += 0x7FFFu + ((u >> 16) & 1u);
    return (ushort)(u >> 16);
}
__device__ __forceinline__ float bf16f(ushort h) {
    return __uint_as_float(((unsigned)h) << 16);
}

// Pre-split W = [Wl; Wr] (256x128 fp32) into bf16 hi/lo packed in B-fragment order:
// frag t = (nt*8 + ks)*64 + lane holds B[k][n], n = nt*16 + (lane&15),
// k = ks*32 + 8*(lane>>4) + j, j = 0..7  -> 16B per lane per frag.
__global__ __launch_bounds__(256) void wprep(const float* __restrict__ Wl,
                                             const float* __restrict__ Wr,
                                             ushort* __restrict__ whi,
                                             ushort* __restrict__ wlo) {
    int t = blockIdx.x * 256 + threadIdx.x;
    if (t >= 8 * 8 * 64) return;
    int lane = t & 63, ks = (t >> 6) & 7, nt = t >> 9;
    int n  = nt * 16 + (lane & 15);
    int kb = ks * 32 + 8 * (lane >> 4);
#pragma unroll
    for (int j = 0; j < 8; ++j) {
        int k = kb + j;
        float w = (k < 128) ? Wl[k * 128 + n] : Wr[(k - 128) * 128 + n];
        ushort hi = bf16_rne(w);
        whi[t * 8 + j] = hi;
        wlo[t * 8 + j] = bf16_rne(w - bf16f(hi));
    }
}

__global__ __launch_bounds__(NTHREADS) void fused_gnn(
    const int*   __restrict__ x_idx,
    const int*   __restrict__ edge_index,
    const float* __restrict__ emb,
    const float* __restrict__ blv,
    const float* __restrict__ pw1,
    const float* __restrict__ pw2,
    const float* __restrict__ W1,
    const float* __restrict__ b1g,
    const float* __restrict__ W3,
    const float* __restrict__ b3g,
    const ushort* __restrict__ whi,
    const ushort* __restrict__ wlo,
    float*       __restrict__ out)
{
    __shared__ __align__(16) float h0[128 * PAD];   // emb rows (later hnew); rows 100..127 zero
    __shared__ __align__(16) int   acnt[128 * PAD]; // edge counts; later meanF / red* / part
    __shared__ int degi[NNODE];
    __shared__ int nid[NNODE];
    __shared__ float score1[NNODE], q2[NNODE], s2v[NNODE];
    __shared__ int   rank1[NNODE], rank2[NNODE];
    __shared__ float xv[2 * DIM];

    float* meanF = reinterpret_cast<float*>(acnt);

    const int g    = blockIdx.x;
    const int tid  = threadIdx.x;
    const int lane = tid & 63;
    const int wv   = tid >> 6;

    // ---- phase 1: zero acnt + h0 pad rows, stage node ids ----
    {
        int4* a4 = reinterpret_cast<int4*>(acnt);
        for (int i = tid; i < 128 * PAD / 4; i += NTHREADS) a4[i] = int4{0, 0, 0, 0};
        float4* hz = reinterpret_cast<float4*>(h0 + 100 * PAD);
        for (int i = tid; i < 28 * PAD / 4; i += NTHREADS) hz[i] = float4{0, 0, 0, 0};
        if (tid < NNODE) { nid[tid] = x_idx[g * NNODE + tid]; degi[tid] = 0; }
    }
    __syncthreads();

    // ---- phase 2: gather embeddings + build count matrix / degrees (int atomics) ----
    {
        const float4* emb4 = reinterpret_cast<const float4*>(emb);
        for (int i = tid; i < NNODE * 32; i += NTHREADS) {
            int n = i >> 5, q = i & 31;
            float4 v = emb4[nid[n] * 32 + q];
            *reinterpret_cast<float4*>(&h0[n * PAD + q * 4]) = v;
        }
        for (int i = tid; i < EPG; i += NTHREADS) {
            int s = edge_index[g * EPG + i] - g * NNODE;
            int d = edge_index[ETOT + g * EPG + i] - g * NNODE;
            atomicAdd(&acnt[d * PAD + s], 1);
            atomicAdd(&degi[d], 1);
        }
    }
    __syncthreads();

    const int mg = wv >> 2, ng = wv & 3;   // 4x4 wave grid; each wave: 2x2 16-tiles

    // ---- phase 5: agg_sum = Acnt @ h0 via MFMA (A exact bf16 counts, B=h0 hi/lo) ----
    {
        f32x4 acc[2][2];
#pragma unroll
        for (int im = 0; im < 2; ++im)
#pragma unroll
            for (int in = 0; in < 2; ++in) acc[im][in] = f32x4{0.f, 0.f, 0.f, 0.f};

        for (int ks = 0; ks < 4; ++ks) {
            const int kb = ks * 32 + 8 * (lane >> 4);
            short8 a[2];
#pragma unroll
            for (int im = 0; im < 2; ++im) {
                int row = (2 * mg + im) * 16 + (lane & 15);
                const int* s = &acnt[row * PAD + kb];
                int4 u0 = *reinterpret_cast<const int4*>(s);
                int4 u1 = *reinterpret_cast<const int4*>(s + 4);
                int vi[8] = {u0.x, u0.y, u0.z, u0.w, u1.x, u1.y, u1.z, u1.w};
#pragma unroll
                for (int j = 0; j < 8; ++j) a[im][j] = (short)bf16_rne((float)vi[j]);
            }
            short8 bh[2], bl2[2];
#pragma unroll
            for (int in = 0; in < 2; ++in) {
                int n = (2 * ng + in) * 16 + (lane & 15);
#pragma unroll
                for (int j = 0; j < 8; ++j) {
                    float v = h0[(kb + j) * PAD + n];
                    ushort hb = bf16_rne(v);
                    bh[in][j]  = (short)hb;
                    bl2[in][j] = (short)bf16_rne(v - bf16f(hb));
                }
            }
#pragma unroll
            for (int im = 0; im < 2; ++im)
#pragma unroll
                for (int in = 0; in < 2; ++in) {
                    acc[im][in] = __builtin_amdgcn_mfma_f32_16x16x32_bf16(a[im], bh[in],  acc[im][in], 0, 0, 0);
                    acc[im][in] = __builtin_amdgcn_mfma_f32_16x16x32_bf16(a[im], bl2[in], acc[im][in], 0, 0, 0);
                }
        }
        __syncthreads();  // all Acnt reads done -> safe to overwrite as meanF
#pragma unroll
        for (int im = 0; im < 2; ++im) {
            int rbase = (2 * mg + im) * 16 + 4 * (lane >> 4);
#pragma unroll
            for (int in = 0; in < 2; ++in) {
                int col = (2 * ng + in) * 16 + (lane & 15);
#pragma unroll
                for (int r = 0; r < 4; ++r) {
                    int row = rbase + r;
                    if (row < NNODE) {
                        float invd = 1.0f / fmaxf((float)degi[row], 1.0f);
                        meanF[row * PAD + col] = acc[im][in][r] * invd;
                    }
                }
            }
        }
    }
    __syncthreads();

    // ---- phase 6: hnew = relu([mean|h0] @ [Wl;Wr] + bl) via MFMA, 3-pass split ----
    {
        f32x4 acc[2][2];
#pragma unroll
        for (int im = 0; im < 2; ++im)
#pragma unroll
            for (int in = 0; in < 2; ++in) acc[im][in] = f32x4{0.f, 0.f, 0.f, 0.f};

        for (int ks = 0; ks < 8; ++ks) {
            const float* Xs = (ks < 4) ? meanF : h0;
            const int kb = (ks & 3) * 32 + 8 * (lane >> 4);
            short8 ah[2], al[2];
#pragma unroll
            for (int im = 0; im < 2; ++im) {
                int row = (2 * mg + im) * 16 + (lane & 15);
                const float* s = &Xs[row * PAD + kb];
                float4 v0 = *reinterpret_cast<const float4*>(s);
                float4 v1 = *reinterpret_cast<const float4*>(s + 4);
                float vf[8] = {v0.x, v0.y, v0.z, v0.w, v1.x, v1.y, v1.z, v1.w};
#pragma unroll
                for (int j = 0; j < 8; ++j) {
                    ushort hb = bf16_rne(vf[j]);
                    ah[im][j] = (short)hb;
                    al[im][j] = (short)bf16_rne(vf[j] - bf16f(hb));
                }
            }
            short8 bh[2], bl2[2];
#pragma unroll
            for (int in = 0; in < 2; ++in) {
                int t = ((2 * ng + in) * 8 + ks) * 64 + lane;
                bh[in]  = *reinterpret_cast<const short8*>(whi + (size_t)t * 8);
                bl2[in] = *reinterpret_cast<const short8*>(wlo + (size_t)t * 8);
            }
#pragma unroll
            for (int im = 0; im < 2; ++im)
#pragma unroll
                for (int in = 0; in < 2; ++in) {
                    acc[im][in] = __builtin_amdgcn_mfma_f32_16x16x32_bf16(ah[im], bh[in],  acc[im][in], 0, 0, 0);
                    acc[im][in] = __builtin_amdgcn_mfma_f32_16x16x32_bf16(al[im], bh[in],  acc[im][in], 0, 0, 0);
                    acc[im][in] = __builtin_amdgcn_mfma_f32_16x16x32_bf16(ah[im], bl2[in], acc[im][in], 0, 0, 0);
                }
        }
        __syncthreads();  // all meanF/h0 reads done -> safe to overwrite h0 with hnew
#pragma unroll
        for (int im = 0; im < 2; ++im) {
            int rbase = (2 * mg + im) * 16 + 4 * (lane >> 4);
#pragma unroll
            for (int in = 0; in < 2; ++in) {
                int col = (2 * ng + in) * 16 + (lane & 15);
                float bc = blv[col];
#pragma unroll
                for (int r = 0; r < 4; ++r) {
                    int row = rbase + r;
                    if (row < NNODE)
                        h0[row * PAD + col] = fmaxf(acc[im][in][r] + bc, 0.0f);
                }
            }
        }
    }
    __syncthreads();

    // ---- phase 7: pooling scores ----
    {
        float a1 = pw1[lane], c1 = pw1[lane + 64];
        float a2 = pw2[lane], c2 = pw2[lane + 64];
        float n1 = a1 * a1 + c1 * c1;
        float n2 = a2 * a2 + c2 * c2;
#pragma unroll
        for (int off = 32; off; off >>= 1) {
            n1 += __shfl_xor(n1, off);
            n2 += __shfl_xor(n2, off);
        }
        float rn1 = 1.0f / sqrtf(n1);
        float rn2 = 1.0f / sqrtf(n2);

        for (int n = wv; n < NNODE; n += 16) {
            float hA = h0[n * PAD + lane], hB = h0[n * PAD + lane + 64];
            float d1 = hA * a1 + hB * c1;
            float d2 = hA * a2 + hB * c2;
#pragma unroll
            for (int off = 32; off; off >>= 1) {
                d1 += __shfl_xor(d1, off);
                d2 += __shfl_xor(d2, off);
            }
            if (lane == 0) {
                score1[n] = tanhf(d1 * rn1);
                q2[n]     = d2 * rn2;
            }
        }
    }
    __syncthreads();

    // ---- phase 8: rank1 (stable top-K1 by counting) + s2 values ----
    if (tid < NNODE) {
        float si = score1[tid];
        int r = 0;
        for (int j = 0; j < NNODE; ++j) {
            float sj = score1[j];
            r += (sj > si || (sj == si && j < tid)) ? 1 : 0;
        }
        rank1[tid] = r;
        s2v[tid] = tanhf(score1[tid] * q2[tid]);
    }
    __syncthreads();

    // ---- phase 9: rank2 among selected (ties by rank1 position) ----
    if (tid < NNODE) {
        int r1i = rank1[tid];
        if (r1i < K1) {
            float si = s2v[tid];
            int r = 0;
            for (int j = 0; j < NNODE; ++j) {
                if (rank1[j] < K1) {
                    float sj = s2v[j];
                    r += (sj > si || (sj == si && rank1[j] < r1i)) ? 1 : 0;
                }
            }
            rank2[tid] = r;
        } else {
            rank2[tid] = 1 << 30;
        }
    }
    __syncthreads();

    // ---- phase 10: readouts (red* buffers alias dead meanF region) ----
    {
        float* redm1 = meanF;
        float* reds1 = meanF + 1024;
        float* redm2 = meanF + 2048;
        float* reds2 = meanF + 3072;
        int f = tid & 127;
        int c = tid >> 7;  // 0..7
        float mx1 = -INFINITY, sm1 = 0.0f, mx2 = -INFINITY, sm2 = 0.0f;
        for (int n = c; n < NNODE; n += 8) {
            if (rank1[n] < K1) {
                float v1 = h0[n * PAD + f] * score1[n];
                mx1 = fmaxf(mx1, v1);
                sm1 += v1;
                if (rank2[n] < K2) {
                    float v2 = v1 * s2v[n];
                    mx2 = fmaxf(mx2, v2);
                    sm2 += v2;
                }
            }
        }
        redm1[c * DIM + f] = mx1; reds1[c * DIM + f] = sm1;
        redm2[c * DIM + f] = mx2; reds2[c * DIM + f] = sm2;
        __syncthreads();
        if (tid < DIM) {
            float m1 = -INFINITY, s1 = 0.0f, m2 = -INFINITY, s2 = 0.0f;
#pragma unroll
            for (int cc = 0; cc < 8; ++cc) {
                m1 = fmaxf(m1, redm1[cc * DIM + tid]); s1 += reds1[cc * DIM + tid];
                m2 = fmaxf(m2, redm2[cc * DIM + tid]); s2 += reds2[cc * DIM + tid];
            }
            xv[tid]       = m1 + m2;
            xv[DIM + tid] = s1 * (1.0f / K1) + s2 * (1.0f / K2);
        }
    }
    __syncthreads();

    // ---- phase 11: MLP head (parallel partials, then 1-wave finish) ----
    {
        float* part = meanF + 4096;  // 16 x 64
        int o = tid & 63, ch = tid >> 6;  // ch 0..15
        float acc = 0.0f;
#pragma unroll
        for (int u = 0; u < 16; ++u) {
            int f = ch * 16 + u;
            acc += xv[f] * W1[f * 64 + o];
        }
        part[ch * 64 + o] = acc;
        __syncthreads();
        if (tid < 64) {
            float a2 = b1g[tid];
#pragma unroll
            for (int cc = 0; cc < 16; ++cc) a2 += part[cc * 64 + tid];
            float y = fmaxf(a2, 0.0f);
            float r = y * W3[tid];
#pragma unroll
            for (int off = 32; off; off >>= 1) r += __shfl_xor(r, off);
            if (tid == 0) out[g] = 1.0f / (1.0f + expf(-(r + b3g[0])));
        }
    }
}

extern "C" void kernel_launch(void* const* d_in, const int* in_sizes, int n_in,
                              void* d_out, int out_size, void* d_ws, size_t ws_size,
                              hipStream_t stream) {
    const int*   x_idx      = (const int*)d_in[0];
    const int*   edge_index = (const int*)d_in[1];
    // d_in[2] = batch (unused)
    const float* emb = (const float*)d_in[3];
    const float* Wl  = (const float*)d_in[4];
    const float* bl  = (const float*)d_in[5];
    const float* Wr  = (const float*)d_in[6];
    const float* pw1 = (const float*)d_in[7];
    const float* pw2 = (const float*)d_in[8];
    const float* W1  = (const float*)d_in[9];
    const float* b1  = (const float*)d_in[10];
    const float* W3  = (const float*)d_in[11];
    const float* b3  = (const float*)d_in[12];
    float* out = (float*)d_out;

    ushort* whi = (ushort*)d_ws;                 // 256*128 bf16 hi = 65536 B
    ushort* wlo = (ushort*)((char*)d_ws + 65536);// 65536 B

    wprep<<<16, 256, 0, stream>>>(Wl, Wr, whi, wlo);
    fused_gnn<<<BGRAPH, NTHREADS, 0, stream>>>(
        x_idx, edge_index, emb, bl, pw1, pw2, W1, b1, W3, b3, whi, wlo, out);
}

// Round 7
// 153.863 us; speedup vs baseline: 4.7706x; 1.0273x over previous
//
#include <hip/hip_runtime.h>
#include <hip/hip_bf16.h>
#include <math.h>

#define BGRAPH 512
#define NNODE  100
#define EPG    1600
#define DIM    128
#define ETOT   (BGRAPH * EPG)   // 819200
#define PAD    132              // fp32/int row stride: 16B-aligned, banks spread
#define K1     80
#define K2     64
#define NTHREADS 1024

typedef __attribute__((ext_vector_type(8))) short short8;   // 8 bf16
typedef __attribute__((ext_vector_type(4))) short short4v;  // 4 bf16
typedef __attribute__((ext_vector_type(4))) float f32x4;    // MFMA acc

__device__ __forceinline__ ushort bf16_rne(float x) {
    unsigned u = __float_as_uint(x);
    u += 0x7FFFu + ((u >> 16) & 1u);
    return (ushort)(u >> 16);
}
__device__ __forceinline__ float bf16f(ushort h) {
    return __uint_as_float(((unsigned)h) << 16);
}

// Pre-split W = [Wl; Wr] (256x128 fp32, K=256 -> block stride 8) into bf16 hi/lo
// B-fragment order: frag t = (nt*8 + ks)*64 + lane holds B[k][n],
// n = nt*16 + (lane&15), k = ks*32 + 8*(lane>>4) + j. ks 0..3 = Wl, 4..7 = Wr.
__global__ __launch_bounds__(256) void wprep(const float* __restrict__ Wl,
                                             const float* __restrict__ Wr,
                                             ushort* __restrict__ whi,
                                             ushort* __restrict__ wlo) {
    int t = blockIdx.x * 256 + threadIdx.x;
    if (t >= 8 * 8 * 64) return;
    int lane = t & 63, ks = (t >> 6) & 7, nt = t >> 9;
    int n  = nt * 16 + (lane & 15);
    int kb = ks * 32 + 8 * (lane >> 4);
#pragma unroll
    for (int j = 0; j < 8; ++j) {
        int k = kb + j;
        float w = (k < 128) ? Wl[k * 128 + n] : Wr[(k - 128) * 128 + n];
        ushort hi = bf16_rne(w);
        whi[t * 8 + j] = hi;
        wlo[t * 8 + j] = bf16_rne(w - bf16f(hi));
    }
}

// K=128 matrices (h0, Acnt, P): block stride 4 ->
//   idx(m,k) = ((m>>4)*4 + (k>>5))*512 + ((m&15) + 16*((k>>3)&3))*8 + (k&7)
// bijective onto [0, 16384). Same formula for B with m -> n column index.

__global__ __launch_bounds__(NTHREADS) void fused_gnn(
    const int*   __restrict__ x_idx,
    const int*   __restrict__ edge_index,
    const float* __restrict__ emb,
    const float* __restrict__ blv,
    const float* __restrict__ pw1,
    const float* __restrict__ pw2,
    const float* __restrict__ W1,
    const float* __restrict__ b1g,
    const float* __restrict__ W3,
    const float* __restrict__ b3g,
    const ushort* __restrict__ whi,
    const ushort* __restrict__ wlo,
    float*       __restrict__ out)
{
    // Region X: h0 f32 -> (in-place) ah hi/lo bf16 -> P hi/lo bf16 -> hnew f32
    __shared__ __align__(16) float Xf[128 * PAD];
    // Region Z: acnt int -> (in-place) abf bf16 -> readout/MLP scratch
    __shared__ __align__(16) int   Zi[128 * PAD];
    __shared__ int degi[NNODE];
    __shared__ int nid[NNODE];
    __shared__ float score1[NNODE], q2[NNODE], s2v[NNODE];
    __shared__ int   rank1[NNODE], rank2[NNODE];
    __shared__ float xv[2 * DIM];

    const int g    = blockIdx.x;
    const int tid  = threadIdx.x;
    const int lane = tid & 63;
    const int wv   = tid >> 6;
    const int mg = wv >> 2, ng = wv & 3;   // 4x4 wave grid; each wave: 2x2 16-tiles

    // ---- P1: zero Z + h0 pad rows, stage node ids ----
    {
        int4* z4 = reinterpret_cast<int4*>(Zi);
        for (int i = tid; i < 128 * PAD / 4; i += NTHREADS) z4[i] = int4{0, 0, 0, 0};
        float4* xz = reinterpret_cast<float4*>(Xf + 100 * PAD);
        for (int i = tid; i < 28 * PAD / 4; i += NTHREADS) xz[i] = float4{0, 0, 0, 0};
        if (tid < NNODE) { nid[tid] = x_idx[g * NNODE + tid]; degi[tid] = 0; }
    }
    __syncthreads();

    // ---- P2: gather embeddings + count matrix / degrees (int atomics) ----
    {
        const float4* emb4 = reinterpret_cast<const float4*>(emb);
        for (int i = tid; i < NNODE * 32; i += NTHREADS) {
            int n = i >> 5, q = i & 31;
            float4 v = emb4[nid[n] * 32 + q];
            *reinterpret_cast<float4*>(&Xf[n * PAD + q * 4]) = v;
        }
        for (int i = tid; i < EPG; i += NTHREADS) {
            int s = edge_index[g * EPG + i] - g * NNODE;
            int d = edge_index[ETOT + g * EPG + i] - g * NNODE;
            atomicAdd(&Zi[d * PAD + s], 1);
            atomicAdd(&degi[d], 1);
        }
    }
    __syncthreads();

    ushort* ahhi = reinterpret_cast<ushort*>(Xf);      // [0, 16384)
    ushort* ahlo = ahhi + 16384;                        // [16384, 32768)
    ushort* abf  = reinterpret_cast<ushort*>(Zi);       // [0, 16384)

    // ---- P3: cooperative one-shot pack (in-place, barrier-staged) ----
    {
        const int m  = tid >> 3;
        const int kb = (tid & 7) * 16;
        float hv[16];
        int   cv[16];
#pragma unroll
        for (int u = 0; u < 4; ++u) {
            float4 v = *reinterpret_cast<const float4*>(&Xf[m * PAD + kb + 4 * u]);
            hv[4 * u] = v.x; hv[4 * u + 1] = v.y; hv[4 * u + 2] = v.z; hv[4 * u + 3] = v.w;
            int4 c = *reinterpret_cast<const int4*>(&Zi[m * PAD + kb + 4 * u]);
            cv[4 * u] = c.x; cv[4 * u + 1] = c.y; cv[4 * u + 2] = c.z; cv[4 * u + 3] = c.w;
        }
        __syncthreads();   // all reads of Xf/Zi complete before overwrite
#pragma unroll
        for (int g2 = 0; g2 < 2; ++g2) {
            int idx = ((m >> 4) * 4 + (kb >> 5)) * 512 +
                      ((m & 15) + 16 * (((kb >> 3) + g2) & 3)) * 8;
            short8 hh, hl, ab;
#pragma unroll
            for (int j = 0; j < 8; ++j) {
                float v = hv[g2 * 8 + j];
                ushort hb = bf16_rne(v);
                hh[j] = (short)hb;
                hl[j] = (short)bf16_rne(v - bf16f(hb));
                ab[j] = (short)bf16_rne((float)cv[g2 * 8 + j]);
            }
            *reinterpret_cast<short8*>(&ahhi[idx]) = hh;
            *reinterpret_cast<short8*>(&ahlo[idx]) = hl;
            *reinterpret_cast<short8*>(&abf[idx])  = ab;
        }
    }
    __syncthreads();

    // ---- P4: P = h0@Wl, Q = h0@Wr (shared A-frags, 3-pass hi/lo split) ----
    f32x4 accP[2][2], accQ[2][2];
#pragma unroll
    for (int im = 0; im < 2; ++im)
#pragma unroll
        for (int in = 0; in < 2; ++in) {
            accP[im][in] = f32x4{0.f, 0.f, 0.f, 0.f};
            accQ[im][in] = f32x4{0.f, 0.f, 0.f, 0.f};
        }
#pragma unroll
    for (int ks = 0; ks < 4; ++ks) {
        short8 Ah[2], Al[2];
#pragma unroll
        for (int im = 0; im < 2; ++im) {
            int fi = (((2 * mg + im) * 4 + ks) * 64 + lane) * 8;
            Ah[im] = *reinterpret_cast<const short8*>(&ahhi[fi]);
            Al[im] = *reinterpret_cast<const short8*>(&ahlo[fi]);
        }
        short8 BhL[2], BlL[2], BhR[2], BlR[2];
#pragma unroll
        for (int in = 0; in < 2; ++in) {
            int nt = 2 * ng + in;
            int tL = ((nt * 8 + ks) * 64 + lane) * 8;       // W layout: K=256, stride 8
            int tR = ((nt * 8 + ks + 4) * 64 + lane) * 8;
            BhL[in] = *reinterpret_cast<const short8*>(whi + tL);
            BlL[in] = *reinterpret_cast<const short8*>(wlo + tL);
            BhR[in] = *reinterpret_cast<const short8*>(whi + tR);
            BlR[in] = *reinterpret_cast<const short8*>(wlo + tR);
        }
#pragma unroll
        for (int im = 0; im < 2; ++im)
#pragma unroll
            for (int in = 0; in < 2; ++in) {
                accP[im][in] = __builtin_amdgcn_mfma_f32_16x16x32_bf16(Ah[im], BhL[in], accP[im][in], 0, 0, 0);
                accP[im][in] = __builtin_amdgcn_mfma_f32_16x16x32_bf16(Al[im], BhL[in], accP[im][in], 0, 0, 0);
                accP[im][in] = __builtin_amdgcn_mfma_f32_16x16x32_bf16(Ah[im], BlL[in], accP[im][in], 0, 0, 0);
                accQ[im][in] = __builtin_amdgcn_mfma_f32_16x16x32_bf16(Ah[im], BhR[in], accQ[im][in], 0, 0, 0);
                accQ[im][in] = __builtin_amdgcn_mfma_f32_16x16x32_bf16(Al[im], BhR[in], accQ[im][in], 0, 0, 0);
                accQ[im][in] = __builtin_amdgcn_mfma_f32_16x16x32_bf16(Ah[im], BlR[in], accQ[im][in], 0, 0, 0);
            }
    }
    __syncthreads();   // all ah reads done -> X reusable for P

    // ---- P5: pack P hi/lo from registers into B-frag layout (rows>=100 exact zeros) ----
    {
        ushort* pbhi = ahhi;           // reuse region X
        ushort* pblo = ahlo;
#pragma unroll
        for (int im = 0; im < 2; ++im) {
            int row0 = (2 * mg + im) * 16 + 4 * (lane >> 4);
#pragma unroll
            for (int in = 0; in < 2; ++in) {
                int col = (2 * ng + in) * 16 + (lane & 15);
                int idx = ((col >> 4) * 4 + (row0 >> 5)) * 512 +
                          ((col & 15) + 16 * ((row0 >> 3) & 3)) * 8 + (row0 & 7);
                short4v h4, l4;
#pragma unroll
                for (int r = 0; r < 4; ++r) {
                    float v = accP[im][in][r];
                    ushort hb = bf16_rne(v);
                    h4[r] = (short)hb;
                    l4[r] = (short)bf16_rne(v - bf16f(hb));
                }
                *reinterpret_cast<short4v*>(&pbhi[idx]) = h4;
                *reinterpret_cast<short4v*>(&pblo[idx]) = l4;
            }
        }
    }
    __syncthreads();

    // ---- P6: R = Acnt @ P (A exact bf16 counts, B = P hi/lo, 2-pass) ----
    f32x4 accR[2][2];
#pragma unroll
    for (int im = 0; im < 2; ++im)
#pragma unroll
        for (int in = 0; in < 2; ++in) accR[im][in] = f32x4{0.f, 0.f, 0.f, 0.f};
#pragma unroll
    for (int ks = 0; ks < 4; ++ks) {
        short8 Ab[2];
#pragma unroll
        for (int im = 0; im < 2; ++im)
            Ab[im] = *reinterpret_cast<const short8*>(&abf[(((2 * mg + im) * 4 + ks) * 64 + lane) * 8]);
        short8 Bh[2], Bl[2];
#pragma unroll
        for (int in = 0; in < 2; ++in) {
            int fi = (((2 * ng + in) * 4 + ks) * 64 + lane) * 8;
            Bh[in] = *reinterpret_cast<const short8*>(&ahhi[fi]);  // = pbhi
            Bl[in] = *reinterpret_cast<const short8*>(&ahlo[fi]);  // = pblo
        }
#pragma unroll
        for (int im = 0; im < 2; ++im)
#pragma unroll
            for (int in = 0; in < 2; ++in) {
                accR[im][in] = __builtin_amdgcn_mfma_f32_16x16x32_bf16(Ab[im], Bh[in], accR[im][in], 0, 0, 0);
                accR[im][in] = __builtin_amdgcn_mfma_f32_16x16x32_bf16(Ab[im], Bl[in], accR[im][in], 0, 0, 0);
            }
    }
    __syncthreads();   // all P reads done -> X reusable as hnew f32

    // ---- P7: hnew = relu(R*invd + Q + bl) -> Xf rows ----
#pragma unroll
    for (int im = 0; im < 2; ++im) {
        int rbase = (2 * mg + im) * 16 + 4 * (lane >> 4);
#pragma unroll
        for (int in = 0; in < 2; ++in) {
            int col = (2 * ng + in) * 16 + (lane & 15);
            float bc = blv[col];
#pragma unroll
            for (int r = 0; r < 4; ++r) {
                int row = rbase + r;
                if (row < NNODE) {
                    float invd = 1.0f / fmaxf((float)degi[row], 1.0f);
                    Xf[row * PAD + col] = fmaxf(accR[im][in][r] * invd + accQ[im][in][r] + bc, 0.0f);
                }
            }
        }
    }
    __syncthreads();

    // ---- P8: pooling scores ----
    {
        float a1 = pw1[lane], c1 = pw1[lane + 64];
        float a2 = pw2[lane], c2 = pw2[lane + 64];
        float n1 = a1 * a1 + c1 * c1;
        float n2 = a2 * a2 + c2 * c2;
#pragma unroll
        for (int off = 32; off; off >>= 1) {
            n1 += __shfl_xor(n1, off);
            n2 += __shfl_xor(n2, off);
        }
        float rn1 = 1.0f / sqrtf(n1);
        float rn2 = 1.0f / sqrtf(n2);

        for (int n = wv; n < NNODE; n += 16) {
            float hA = Xf[n * PAD + lane], hB = Xf[n * PAD + lane + 64];
            float d1 = hA * a1 + hB * c1;
            float d2 = hA * a2 + hB * c2;
#pragma unroll
            for (int off = 32; off; off >>= 1) {
                d1 += __shfl_xor(d1, off);
                d2 += __shfl_xor(d2, off);
            }
            if (lane == 0) {
                score1[n] = tanhf(d1 * rn1);
                q2[n]     = d2 * rn2;
            }
        }
    }
    __syncthreads();

    // ---- P9: rank1 (stable top-K1 by counting) + s2 values ----
    if (tid < NNODE) {
        float si = score1[tid];
        int r = 0;
        for (int j = 0; j < NNODE; ++j) {
            float sj = score1[j];
            r += (sj > si || (sj == si && j < tid)) ? 1 : 0;
        }
        rank1[tid] = r;
        s2v[tid] = tanhf(score1[tid] * q2[tid]);
    }
    __syncthreads();

    // ---- P10: rank2 among selected (ties by rank1 position) ----
    if (tid < NNODE) {
        int r1i = rank1[tid];
        if (r1i < K1) {
            float si = s2v[tid];
            int r = 0;
            for (int j = 0; j < NNODE; ++j) {
                if (rank1[j] < K1) {
                    float sj = s2v[j];
                    r += (sj > si || (sj == si && rank1[j] < r1i)) ? 1 : 0;
                }
            }
            rank2[tid] = r;
        } else {
            rank2[tid] = 1 << 30;
        }
    }
    __syncthreads();

    // ---- P11: readouts (scratch in Z region; abf is dead) ----
    {
        float* Zf = reinterpret_cast<float*>(Zi);
        float* redm1 = Zf;
        float* reds1 = Zf + 1024;
        float* redm2 = Zf + 2048;
        float* reds2 = Zf + 3072;
        int f = tid & 127;
        int c = tid >> 7;  // 0..7
        float mx1 = -INFINITY, sm1 = 0.0f, mx2 = -INFINITY, sm2 = 0.0f;
        for (int n = c; n < NNODE; n += 8) {
            if (rank1[n] < K1) {
                float v1 = Xf[n * PAD + f] * score1[n];
                mx1 = fmaxf(mx1, v1);
                sm1 += v1;
                if (rank2[n] < K2) {
                    float v2 = v1 * s2v[n];
                    mx2 = fmaxf(mx2, v2);
                    sm2 += v2;
                }
            }
        }
        redm1[c * DIM + f] = mx1; reds1[c * DIM + f] = sm1;
        redm2[c * DIM + f] = mx2; reds2[c * DIM + f] = sm2;
        __syncthreads();
        if (tid < DIM) {
            float m1 = -INFINITY, s1 = 0.0f, m2 = -INFINITY, s2 = 0.0f;
#pragma unroll
            for (int cc = 0; cc < 8; ++cc) {
                m1 = fmaxf(m1, redm1[cc * DIM + tid]); s1 += reds1[cc * DIM + tid];
                m2 = fmaxf(m2, redm2[cc * DIM + tid]); s2 += reds2[cc * DIM + tid];
            }
            xv[tid]       = m1 + m2;
            xv[DIM + tid] = s1 * (1.0f / K1) + s2 * (1.0f / K2);
        }
    }
    __syncthreads();

    // ---- P12: MLP head ----
    {
        float* Zf = reinterpret_cast<float*>(Zi);
        float* part = Zf + 4096;  // 16 x 64
        int o = tid & 63, ch = tid >> 6;  // ch 0..15
        float acc = 0.0f;
#pragma unroll
        for (int u = 0; u < 16; ++u) {
            int f = ch * 16 + u;
            acc += xv[f] * W1[f * 64 + o];
        }
        part[ch * 64 + o] = acc;
        __syncthreads();
        if (tid < 64) {
            float a2 = b1g[tid];
#pragma unroll
            for (int cc = 0; cc < 16; ++cc) a2 += part[cc * 64 + tid];
            float y = fmaxf(a2, 0.0f);
            float r = y * W3[tid];
#pragma unroll
            for (int off = 32; off; off >>= 1) r += __shfl_xor(r, off);
            if (tid == 0) out[g] = 1.0f / (1.0f + expf(-(r + b3g[0])));
        }
    }
}

extern "C" void kernel_launch(void* const* d_in, const int* in_sizes, int n_in,
                              void* d_out, int out_size, void* d_ws, size_t ws_size,
                              hipStream_t stream) {
    const int*   x_idx      = (const int*)d_in[0];
    const int*   edge_index = (const int*)d_in[1];
    // d_in[2] = batch (unused)
    const float* emb = (const float*)d_in[3];
    const float* Wl  = (const float*)d_in[4];
    const float* bl  = (const float*)d_in[5];
    const float* Wr  = (const float*)d_in[6];
    const float* pw1 = (const float*)d_in[7];
    const float* pw2 = (const float*)d_in[8];
    const float* W1  = (const float*)d_in[9];
    const float* b1  = (const float*)d_in[10];
    const float* W3  = (const float*)d_in[11];
    const float* b3  = (const float*)d_in[12];
    float* out = (float*)d_out;

    ushort* whi = (ushort*)d_ws;                  // 256*128 bf16 hi = 65536 B
    ushort* wlo = (ushort*)((char*)d_ws + 65536); // 65536 B

    wprep<<<16, 256, 0, stream>>>(Wl, Wr, whi, wlo);
    fused_gnn<<<BGRAPH, NTHREADS, 0, stream>>>(
        x_idx, edge_index, emb, bl, pw1, pw2, W1, b1, W3, b3, whi, wlo, out);
}